// Round 8
// baseline (138.702 us; speedup 1.0000x reference)
//
#include <hip/hip_runtime.h>
#include <hip/hip_bf16.h>
#include <math.h>
#include <stdint.h>

#define BATCH 64
#define SEQ   101
#define HID   512
#define NKQ   100      // N*K
#define KCLS  10
#define INV_TEMP 0.04419417382415922f   // 1/sqrt(512)

typedef short bf16x8 __attribute__((ext_vector_type(8)));
typedef float f32x4  __attribute__((ext_vector_type(4)));
typedef uint32_t u32x4 __attribute__((ext_vector_type(4)));

// packed f32->bf16 RNE via compiler intrinsic (v_cvt_pk_bf16_f32).
__device__ inline uint32_t cvt2(float a, float b) {
    __hip_bfloat162 t = __float22bfloat162_rn(float2{a, b});
    uint32_t r;
    __builtin_memcpy(&r, &t, 4);
    return r;
}
// truncation split: x == hi + lo to ~2^-17 rel (q & P planes)
__device__ inline void split_bf16(float x, short& hi, short& lo) {
    uint32_t u = __builtin_bit_cast(uint32_t, x);
    hi = (short)(u >> 16);
    float hf = __builtin_bit_cast(float, u & 0xFFFF0000u);
    float l  = x - hf;
    lo = (short)(__builtin_bit_cast(uint32_t, l) >> 16);
}

// ---------------------------------------------------------------------------
// h-SPLIT fused kernel: grid 896 = 64 b x 7 i-tiles x 2 h-halves.
//   id: b = id&63 (XCD affinity: same-b blocks all hit one XCD's L2 for k/v),
//       hh = (id>>6)&1 (h-half), i-tile = id>>7.
// Phases 1-2 (QK^T + softmax) are computed REDUNDANTLY by both h-halves
// (k is L2-hot; we are latency-bound, redundant parallel work is cheap).
// Phase 3 runs only 2 of 4 h-chunks -> per-wave critical path halves.
// This is also a measurement: if time does NOT drop, phases 1-2 own the
// per-wave latency and the next move is restructuring QK^T/softmax.
// Phase 1 reverted to depth-1 prefetch (round 4's best-measured form).
// attn written only by hh==0 blocks. LDS 41 KB -> 3 blocks/CU.
// ---------------------------------------------------------------------------
#define QST 520    // qhi/qlo row stride (shorts): 512 + 8 pad

#define OFF_QLO 16640          // 16*520*2
#define POOLSZ  33280          // 2*16640

__global__ __launch_bounds__(512, 2)
void fused_attn(const float* __restrict__ q, const float* __restrict__ k,
                const float* __restrict__ v, const float* __restrict__ aw,
                float* __restrict__ out, float* __restrict__ attn) {
    __shared__ __align__(16) char pool[POOLSZ];
    __shared__ __align__(16) float sc[16][132];
    short (*qhi)[QST] = (short(*)[QST])(pool);
    short (*qlo)[QST] = (short(*)[QST])(pool + OFF_QLO);

    const int b   = blockIdx.x & 63;
    const int hh  = (blockIdx.x >> 6) & 1;
    const int i0  = (blockIdx.x >> 7) * 16;
    const int tid = threadIdx.x;
    const int wv  = tid >> 6, lane = tid & 63;
    const int m   = lane & 15;
    const int g   = lane >> 4;
    const int kq  = g * 8;
    const int rq  = g * 4;
    const int j0w = wv * 16;

    const float* qb = q + (size_t)b * SEQ * HID;
    const float* kb = k + (size_t)b * SEQ * HID;
    const float* vb = v + (size_t)b * SEQ * HID;

    // ---------------- stage q hi/lo (once) ---------------------------------
    #pragma unroll
    for (int s = 0; s < 4; ++s) {
        const int f = tid + s * 512;
        const int r = f >> 7, c = (f & 127) << 2;
        const int gi = i0 + r;
        f32x4 x = {};
        if (gi < SEQ) x = *(const f32x4*)(qb + (size_t)gi * HID + c);
        short4 hv, lv;
        split_bf16(x[0], hv.x, lv.x);
        split_bf16(x[1], hv.y, lv.y);
        split_bf16(x[2], hv.z, lv.z);
        split_bf16(x[3], hv.w, lv.w);
        *(short4*)&qhi[r][c] = hv;
        *(short4*)&qlo[r][c] = lv;
    }
    __syncthreads();

    // ---------------- phase 1: QK^T, k direct from global, depth-1 ---------
    f32x4 acc = {};
    {
        const int jg = j0w + m;
        const int jr = (jg > NKQ) ? NKQ : jg;   // clamp; junk cols zeroed later
        const float* kr = kb + (size_t)jr * HID + kq;
        f32x4 k0 = *(const f32x4*)(kr);
        f32x4 k1 = *(const f32x4*)(kr + 4);
        #pragma unroll
        for (int ks = 0; ks < 16; ++ks) {
            f32x4 n0 = {}, n1 = {};
            if (ks < 15) {
                n0 = *(const f32x4*)(kr + (ks + 1) * 32);
                n1 = *(const f32x4*)(kr + (ks + 1) * 32 + 4);
            }
            u32x4 kw;
            kw[0] = cvt2(k0[0], k0[1]); kw[1] = cvt2(k0[2], k0[3]);
            kw[2] = cvt2(k1[0], k1[1]); kw[3] = cvt2(k1[2], k1[3]);
            const bf16x8 kH = __builtin_bit_cast(bf16x8, kw);
            const bf16x8 qH = *(const bf16x8*)&qhi[m][ks * 32 + kq];
            const bf16x8 qL = *(const bf16x8*)&qlo[m][ks * 32 + kq];
            acc = __builtin_amdgcn_mfma_f32_16x16x32_bf16(qH, kH, acc, 0, 0, 0);
            acc = __builtin_amdgcn_mfma_f32_16x16x32_bf16(qL, kH, acc, 0, 0, 0);
            k0 = n0; k1 = n1;
        }
    }
    #pragma unroll
    for (int r = 0; r < 4; ++r)
        sc[rq + r][j0w + m] = acc[r];
    __syncthreads();

    // ---------------- phase 2: softmax; normalized P stays in sc -----------
    {
        const int row = tid >> 5, t32 = tid & 31;
        const int gi  = i0 + row;
        float mx = -1e30f;
        for (int j = t32; j < SEQ; j += 32) {
            float s = sc[row][j] * INV_TEMP;
            sc[row][j] = s;
            mx = fmaxf(mx, s);
        }
        #pragma unroll
        for (int off = 1; off < 32; off <<= 1) mx = fmaxf(mx, __shfl_xor(mx, off));
        float sum = 0.f;
        for (int j = t32; j < SEQ; j += 32) {
            float e = __expf(sc[row][j] - mx);
            sc[row][j] = e;
            sum += e;
        }
        #pragma unroll
        for (int off = 1; off < 32; off <<= 1) sum += __shfl_xor(sum, off);
        const float inv = 1.f / sum;
        float* arow = attn + ((size_t)b * SEQ + gi) * SEQ;
        for (int j = t32; j < SEQ; j += 32) {
            float a = sc[row][j] * inv;
            sc[row][j] = a;                       // PV reads P from LDS
            if (hh == 0 && gi < SEQ) arow[j] = a; // tuple output, once
        }
        for (int j = SEQ + t32; j < 128; j += 32) sc[row][j] = 0.f;  // pad cols
    }
    __syncthreads();

    // ---------------- A fragments + class mask (hoisted) --------------------
    int ai = i0 + m; if (ai > NKQ) ai = NKQ;
    const int ci = ai / KCLS;
    uint32_t mbits = 0;
    #pragma unroll
    for (int ks = 0; ks < 4; ++ks)
        #pragma unroll
        for (int e = 0; e < 8; ++e)
            if (((ks * 32 + kq + e) / KCLS) == ci) mbits |= (1u << (ks * 8 + e));
    bf16x8 Ah[4], Al[4];
    #pragma unroll
    for (int ks = 0; ks < 4; ++ks) {
        const f32x4 u0 = *(const f32x4*)&sc[m][ks * 32 + kq];
        const f32x4 u1 = *(const f32x4*)&sc[m][ks * 32 + kq + 4];
        const float x[8] = {u0[0], u0[1], u0[2], u0[3], u1[0], u1[1], u1[2], u1[3]};
        #pragma unroll
        for (int e = 0; e < 8; ++e) {
            short h, l; split_bf16(x[e], h, l);
            Ah[ks][e] = h; Al[ks][e] = l;
        }
    }

    // ---------------- phase 3: PV direct-from-global, 2 h-chunks ------------
    const int hl = j0w + m;                    // local h (0..127) this lane owns
    #pragma unroll
    for (int hcl = 0; hcl < 2; ++hcl) {
        const int hc = hh * 2 + hcl;           // uniform scalar, address-only
        const int h = (hc << 7) + hl;
        const float* vh = vb + h;
        // early-issue epilogue data (independent; overlaps with MFMA below)
        const float w0 = aw[0 * HID + h], w1 = aw[1 * HID + h], w2 = aw[2 * HID + h];
        const float w3 = aw[3 * HID + h], w4 = aw[4 * HID + h], w5 = aw[5 * HID + h];
        const float vN = vh[(size_t)NKQ * HID];
        float vi_r[4];
        #pragma unroll
        for (int r = 0; r < 4; ++r) {
            const int i = i0 + rq + r;
            vi_r[r] = (i < NKQ) ? vh[(size_t)i * HID] : 0.f;
        }

        f32x4 T = {}, U = {};
        float xv[2][8];
        #pragma unroll
        for (int e = 0; e < 8; ++e) {          // ks=0 gather
            const int j = kq + e;
            xv[0][e] = vh[(size_t)j * HID];
        }
        #pragma unroll
        for (int ks = 0; ks < 4; ++ks) {
            const int cur = ks & 1;            // static after unroll
            if (ks < 3) {                      // prefetch next ks gather
                #pragma unroll
                for (int e = 0; e < 8; ++e) {
                    const int j  = (ks + 1) * 32 + kq + e;
                    const int jr = (j > NKQ) ? NKQ : j;   // P=0 there nullifies
                    xv[cur ^ 1][e] = vh[(size_t)jr * HID];
                }
            }
            u32x4 ph, pl;
            #pragma unroll
            for (int p = 0; p < 4; ++p) {
                const float a0 = xv[cur][2 * p], a1 = xv[cur][2 * p + 1];
                const uint32_t h01 = cvt2(a0, a1);
                ph[p] = h01;
                pl[p] = cvt2(a0 - __builtin_bit_cast(float, h01 << 16),
                             a1 - __builtin_bit_cast(float, h01 & 0xFFFF0000u));
            }
            const bf16x8 Bh = __builtin_bit_cast(bf16x8, ph);
            const bf16x8 Bl = __builtin_bit_cast(bf16x8, pl);
            bf16x8 Mh;
            #pragma unroll
            for (int e = 0; e < 8; ++e)
                Mh[e] = (mbits & (1u << (ks * 8 + e))) ? Ah[ks][e] : (short)0;
            T = __builtin_amdgcn_mfma_f32_16x16x32_bf16(Ah[ks], Bh, T, 0, 0, 0);
            T = __builtin_amdgcn_mfma_f32_16x16x32_bf16(Ah[ks], Bl, T, 0, 0, 0);
            T = __builtin_amdgcn_mfma_f32_16x16x32_bf16(Al[ks], Bh, T, 0, 0, 0);
            U = __builtin_amdgcn_mfma_f32_16x16x32_bf16(Mh,     Bh, U, 0, 0, 0);
        }
        // epilogue for this h-chunk
        #pragma unroll
        for (int r = 0; r < 4; ++r) {
            const int i = i0 + rq + r;
            if (i >= SEQ) continue;
            const int il = rq + r;
            const float t = T[r], u = U[r];
            const float aiN = sc[il][NKQ];
            float o;
            if (i < NKQ) {
                const float aii = sc[il][i];
                o = w2 * t + (w1 - w2) * u + (w0 - w1) * aii * vi_r[r] + (w3 - w2) * aiN * vN;
            } else {
                o = w4 * t + (w5 - w4) * aiN * vN;
            }
            out[((size_t)b * SEQ + i) * HID + h] = o;
        }
    }
}

extern "C" void kernel_launch(void* const* d_in, const int* in_sizes, int n_in,
                              void* d_out, int out_size, void* d_ws, size_t ws_size,
                              hipStream_t stream) {
    const float* q  = (const float*)d_in[0];
    const float* k  = (const float*)d_in[1];
    const float* v  = (const float*)d_in[2];
    const float* aw = (const float*)d_in[3];
    float* out  = (float*)d_out;
    float* attn = out + (size_t)BATCH * SEQ * HID;   // tuple output: [out | attn]
    (void)d_ws; (void)ws_size;

    fused_attn<<<dim3(896), dim3(512), 0, stream>>>(q, k, v, aw, out, attn);
}

// Round 9
// 114.282 us; speedup vs baseline: 1.2137x; 1.2137x over previous
//
#include <hip/hip_runtime.h>
#include <hip/hip_bf16.h>
#include <math.h>
#include <stdint.h>

#define BATCH 64
#define SEQ   101
#define HID   512
#define NKQ   100      // N*K
#define KCLS  10
#define INV_TEMP 0.04419417382415922f   // 1/sqrt(512)

typedef short bf16x8 __attribute__((ext_vector_type(8)));
typedef float f32x4  __attribute__((ext_vector_type(4)));
typedef uint32_t u32x4 __attribute__((ext_vector_type(4)));

__device__ inline f32x4 vspl(float x) { return (f32x4){x, x, x, x}; }

// packed f32->bf16 RNE via compiler intrinsic (v_cvt_pk_bf16_f32).
__device__ inline uint32_t cvt2(float a, float b) {
    __hip_bfloat162 t = __float22bfloat162_rn(float2{a, b});
    uint32_t r;
    __builtin_memcpy(&r, &t, 4);
    return r;
}
// truncation split: x == hi + lo to ~2^-17 rel (q plane)
__device__ inline void split_bf16(float x, short& hi, short& lo) {
    uint32_t u = __builtin_bit_cast(uint32_t, x);
    hi = (short)(u >> 16);
    float hf = __builtin_bit_cast(float, u & 0xFFFF0000u);
    float l  = x - hf;
    lo = (short)(__builtin_bit_cast(uint32_t, l) >> 16);
}

// ---------------------------------------------------------------------------
// Kernel 0 (prep): K -> bf16 RNE plane in workspace. Pure streaming,
// coalesced float4 -> 8B bf16x4. ~20 MB traffic, BW-bound, high TLP.
// ---------------------------------------------------------------------------
__global__ __launch_bounds__(256)
void prep_k(const float* __restrict__ k, uint32_t* __restrict__ kp) {
    const int total = BATCH * SEQ * HID / 4;   // float4 count = 827,392
    for (int i = blockIdx.x * 256 + threadIdx.x; i < total; i += gridDim.x * 256) {
        const f32x4 x = ((const f32x4*)k)[i];
        kp[2 * i + 0] = cvt2(x[0], x[1]);
        kp[2 * i + 1] = cvt2(x[2], x[3]);
    }
}

// ---------------------------------------------------------------------------
// Kernel 1 (fused), redesigned for latency + I$:
//   phase 1: QK^T -- q hi/lo staged in LDS (1 barrier); K read as bf16 from
//            prep plane: 16 independent b128 loads preloaded to regs (MLP 16),
//            zero conversion VALU. Values bit-identical to old cvt2 path.
//   phase 2: softmax, P normalized into LDS sc (fp32).
//   phase 3: fp32 STREAMING PV (no MFMA, no bf16): thread = 4 h-cols x 4
//            i-rows; loop j=0..99 with coalesced float4 V loads + LDS
//            broadcast P. U (same-class sum) via class-segmented accumulation
//            (class = contiguous 10-j window) -- one select per class.
//            Epilogue fused. PV is now fp32-exact (accuracy improves).
// Code size ~800 instr (vs ~3-4K fully-unrolled gather version) -> I$-resident.
// LDS: q hi/lo 32.5 KB + sc 8.4 KB. grid 448: b=id&63 (XCD affinity for k/v
// L2 reuse), i-tile=id>>6. 512 thr = 8 waves, __launch_bounds__(512,2).
// ---------------------------------------------------------------------------
#define QST 520    // qhi/qlo row stride (shorts): 512 + 8 pad

#define OFF_QLO 16640          // 16*520*2
#define POOLSZ  33280          // 2*16640

__global__ __launch_bounds__(512, 2)
void fused_attn(const float* __restrict__ q, const short* __restrict__ kp,
                const float* __restrict__ v, const float* __restrict__ aw,
                float* __restrict__ out, float* __restrict__ attn) {
    __shared__ __align__(16) char pool[POOLSZ];
    __shared__ __align__(16) float sc[16][132];
    short (*qhi)[QST] = (short(*)[QST])(pool);
    short (*qlo)[QST] = (short(*)[QST])(pool + OFF_QLO);

    const int b   = blockIdx.x & 63;
    const int i0  = (blockIdx.x >> 6) * 16;
    const int tid = threadIdx.x;
    const int wv  = tid >> 6, lane = tid & 63;
    const int m   = lane & 15;
    const int g   = lane >> 4;
    const int kq  = g * 8;
    const int rq  = g * 4;
    const int j0w = wv * 16;

    const float* qb = q + (size_t)b * SEQ * HID;
    const short* kb = kp + (size_t)b * SEQ * HID;
    const float* vb = v + (size_t)b * SEQ * HID;

    // ---------------- stage q hi/lo (once) ---------------------------------
    #pragma unroll
    for (int s = 0; s < 4; ++s) {
        const int f = tid + s * 512;
        const int r = f >> 7, c = (f & 127) << 2;
        const int gi = i0 + r;
        f32x4 x = {};
        if (gi < SEQ) x = *(const f32x4*)(qb + (size_t)gi * HID + c);
        short4 hv, lv;
        split_bf16(x[0], hv.x, lv.x);
        split_bf16(x[1], hv.y, lv.y);
        split_bf16(x[2], hv.z, lv.z);
        split_bf16(x[3], hv.w, lv.w);
        *(short4*)&qhi[r][c] = hv;
        *(short4*)&qlo[r][c] = lv;
    }
    __syncthreads();

    // ---------------- phase 1: QK^T, K bf16 preloaded (MLP 16) -------------
    f32x4 acc = {};
    {
        const int jg = j0w + m;
        const int jr = (jg > NKQ) ? NKQ : jg;   // clamp; junk rows finite
        const short* krow = kb + (size_t)jr * HID + kq;
        bf16x8 kf[16];
        #pragma unroll
        for (int ks = 0; ks < 16; ++ks)
            kf[ks] = *(const bf16x8*)(krow + ks * 32);
        #pragma unroll
        for (int ks = 0; ks < 16; ++ks) {
            const bf16x8 qH = *(const bf16x8*)&qhi[m][ks * 32 + kq];
            const bf16x8 qL = *(const bf16x8*)&qlo[m][ks * 32 + kq];
            acc = __builtin_amdgcn_mfma_f32_16x16x32_bf16(qH, kf[ks], acc, 0, 0, 0);
            acc = __builtin_amdgcn_mfma_f32_16x16x32_bf16(qL, kf[ks], acc, 0, 0, 0);
        }
    }
    #pragma unroll
    for (int r = 0; r < 4; ++r)
        sc[rq + r][j0w + m] = acc[r];
    __syncthreads();

    // ---------------- phase 2: softmax; normalized P stays in sc -----------
    {
        const int row = tid >> 5, t32 = tid & 31;
        const int gi  = i0 + row;
        float mx = -1e30f;
        for (int j = t32; j < SEQ; j += 32) {
            float s = sc[row][j] * INV_TEMP;
            sc[row][j] = s;
            mx = fmaxf(mx, s);
        }
        #pragma unroll
        for (int off = 1; off < 32; off <<= 1) mx = fmaxf(mx, __shfl_xor(mx, off));
        float sum = 0.f;
        for (int j = t32; j < SEQ; j += 32) {
            float e = __expf(sc[row][j] - mx);
            sc[row][j] = e;
            sum += e;
        }
        #pragma unroll
        for (int off = 1; off < 32; off <<= 1) sum += __shfl_xor(sum, off);
        const float inv = 1.f / sum;
        float* arow = attn + ((size_t)b * SEQ + gi) * SEQ;
        for (int j = t32; j < SEQ; j += 32) {
            float a = sc[row][j] * inv;
            sc[row][j] = a;                 // PV reads P from LDS
            if (gi < SEQ) arow[j] = a;      // tuple output
        }
    }
    __syncthreads();

    // ---------------- phase 3: fp32 streaming PV + epilogue -----------------
    {
        const int hp = tid & 127;          // float4 column index
        const int rg = tid >> 7;           // 0..3 -> rows rg*4..rg*4+3
        const int h4 = hp << 2;
        const float* vcol = vb + h4;

        int cir[4];
        #pragma unroll
        for (int rr = 0; rr < 4; ++rr)
            cir[rr] = (i0 + rg * 4 + rr) / KCLS;   // class of row (>=10 for junk)

        f32x4 accT[4] = {}, accU[4] = {};
        #pragma unroll 1
        for (int cls = 0; cls < 10; ++cls) {
            f32x4 seg[4] = {};
            const int jb = cls * KCLS;
            #pragma unroll 5
            for (int t = 0; t < KCLS; ++t) {
                const int j = jb + t;
                const f32x4 vj = *(const f32x4*)(vcol + (size_t)j * HID);
                #pragma unroll
                for (int rr = 0; rr < 4; ++rr) {
                    const float p = sc[rg * 4 + rr][j];
                    seg[rr] += vspl(p) * vj;
                }
            }
            #pragma unroll
            for (int rr = 0; rr < 4; ++rr) {
                accT[rr] += seg[rr];
                if (cls == cir[rr]) accU[rr] = seg[rr];   // wave-uniform select
            }
        }
        // j = 100 (query row) contributes to T only
        const f32x4 vN4 = *(const f32x4*)(vcol + (size_t)NKQ * HID);
        #pragma unroll
        for (int rr = 0; rr < 4; ++rr)
            accT[rr] += vspl(sc[rg * 4 + rr][NKQ]) * vN4;

        // epilogue (all fp32, float4-wide)
        const f32x4 w0 = *(const f32x4*)(aw + 0 * HID + h4);
        const f32x4 w1 = *(const f32x4*)(aw + 1 * HID + h4);
        const f32x4 w2 = *(const f32x4*)(aw + 2 * HID + h4);
        const f32x4 w3 = *(const f32x4*)(aw + 3 * HID + h4);
        const f32x4 w4 = *(const f32x4*)(aw + 4 * HID + h4);
        const f32x4 w5 = *(const f32x4*)(aw + 5 * HID + h4);
        #pragma unroll
        for (int rr = 0; rr < 4; ++rr) {
            const int il = rg * 4 + rr;
            const int i  = i0 + il;
            if (i >= SEQ) continue;
            const float aiN = sc[il][NKQ];
            f32x4 o;
            if (i < NKQ) {
                const float aii = sc[il][i];
                const f32x4 vi  = *(const f32x4*)(vcol + (size_t)i * HID);
                o = w2 * accT[rr] + (w1 - w2) * accU[rr]
                  + (w0 - w1) * vspl(aii) * vi
                  + (w3 - w2) * vspl(aiN) * vN4;
            } else {
                o = w4 * accT[rr] + (w5 - w4) * vspl(aiN) * vN4;
            }
            *(f32x4*)(out + ((size_t)b * SEQ + i) * HID + h4) = o;
        }
    }
}

extern "C" void kernel_launch(void* const* d_in, const int* in_sizes, int n_in,
                              void* d_out, int out_size, void* d_ws, size_t ws_size,
                              hipStream_t stream) {
    const float* q  = (const float*)d_in[0];
    const float* k  = (const float*)d_in[1];
    const float* v  = (const float*)d_in[2];
    const float* aw = (const float*)d_in[3];
    float* out  = (float*)d_out;
    float* attn = out + (size_t)BATCH * SEQ * HID;   // tuple output: [out | attn]
    uint32_t* kp = (uint32_t*)d_ws;                  // bf16 K plane, 6.6 MB

    prep_k<<<dim3(512), dim3(256), 0, stream>>>(k, kp);
    fused_attn<<<dim3(448), dim3(512), 0, stream>>>(q, (const short*)kp, v, aw,
                                                    out, attn);
}